// Round 13
// baseline (124.532 us; speedup 1.0000x reference)
//
#include <hip/hip_runtime.h>
#include <hip/hip_bf16.h>
#include <math.h>

// Problem constants
#define NB   8
#define TCTX 4096
#define ED   1024
#define KD   64

typedef __attribute__((ext_vector_type(8))) short bf16x8;
typedef __attribute__((ext_vector_type(4))) float f32x4;

#define LOG2E  1.44269504088896340736f
#define SCALE2 (0.125f * LOG2E)          // folded into Q at projection time
#define MASK2  (-1e10f * LOG2E)          // -1e10 in log2 domain

// LGKM ops complete OUT OF ORDER: ds_read after ds_write needs lgkmcnt(0)
// (R8/R9 lesson). sched_barrier(0) stops MFMA hoisting past the asm wait.
__device__ __forceinline__ void lds_fence() {
    asm volatile("s_waitcnt lgkmcnt(0)" ::: "memory");
    __builtin_amdgcn_sched_barrier(0);
}

__device__ __forceinline__ unsigned short f2bf(float f) {
    union { float f; unsigned u; } c; c.f = f;
    return (unsigned short)((c.u + 0x7FFFu + ((c.u >> 16) & 1u)) >> 16);
}
__device__ __forceinline__ int swz(int row, int byteoff) {
    return row * 128 + (byteoff ^ ((row & 7) << 4));
}
__device__ __forceinline__ f32x4 fzero4() {
    f32x4 z; z[0] = 0.f; z[1] = 0.f; z[2] = 0.f; z[3] = 0.f; return z;
}
__device__ __forceinline__ void gl_lds16(const void* g, void* l) {
    __builtin_amdgcn_global_load_lds(
        (const __attribute__((address_space(1))) unsigned int*)g,
        (__attribute__((address_space(3))) unsigned int*)l, 16, 0, 0);
}
__device__ __forceinline__ unsigned cvtpk_bf16(float lo, float hi) {
    unsigned r;
    asm("v_cvt_pk_bf16_f32 %0, %1, %2" : "=v"(r) : "v"(lo), "v"(hi));
    return r;
}

// ---------------------------------------------------------------------------
// Prep kernel: one-time weight repack (fp32 -> bf16).  (unchanged, passing)
// ---------------------------------------------------------------------------
__global__ __launch_bounds__(256) void prep_kernel(
    const float* __restrict__ kw1, const float* __restrict__ qw1,
    const float* __restrict__ vw,  const float* __restrict__ kw2,
    const float* __restrict__ qw2,
    unsigned short* __restrict__ W1p, unsigned short* __restrict__ W2p)
{
    int idx = blockIdx.x * 256 + threadIdx.x;   // 16B-block index
    if (idx < 24576) {
        int ks = idx / 1536, rem = idx % 1536;
        int r = rem >> 3, bb = rem & 7;
        int c = bb ^ (r & 7);
        const float* src = (r < 64)  ? (kw1 + r * ED)
                         : (r < 128) ? (qw1 + (r - 64) * ED)
                                     : (vw  + (r - 128) * ED);
        src += ks * 64 + c * 8;
        unsigned short* dst = W1p + (size_t)idx * 8;
        #pragma unroll
        for (int e = 0; e < 8; ++e) dst[e] = f2bf(src[e]);
    } else if (idx < 25600) {
        int j = idx - 24576;
        int lane = j & 63, kh = (j >> 6) & 1, n = (j >> 7) & 3, kq = j >> 9;
        int row = n * 16 + (lane & 15);
        int ko  = kh * 32 + (lane >> 4) * 8;
        const float* src = (kq ? qw2 : kw2) + row * 64 + ko;
        unsigned short* dst = W2p + (size_t)j * 8;
        #pragma unroll
        for (int e = 0; e < 8; ++e) dst[e] = f2bf(src[e]);
    }
}

// ---------------------------------------------------------------------------
// Projection kernel (unchanged, passing).
// ---------------------------------------------------------------------------
__global__ __launch_bounds__(256, 2) void proj_kernel(
    const float* __restrict__ emb,
    const unsigned short* __restrict__ W1p, const unsigned short* __restrict__ W2p,
    const float* __restrict__ kb1, const float* __restrict__ kb2,
    const float* __restrict__ qb1, const float* __restrict__ qb2,
    const float* __restrict__ vb,
    unsigned short* __restrict__ Qo, unsigned short* __restrict__ Ko,
    unsigned short* __restrict__ Vt)
{
    __shared__ __align__(16) char lds[80 * 1024];

    const int tid  = threadIdx.x;
    const int lane = tid & 63;
    const int w    = tid >> 6;
    const int lr   = lane & 15;
    const int lg   = lane >> 4;
    const long r0  = (long)blockIdx.x * 64;
    const int  b   = blockIdx.x >> 6;
    const int  tb  = (blockIdx.x & 63) * 64;

    const float* embB = emb + r0 * ED;

    f32x4 acc[12];
    #pragma unroll
    for (int j = 0; j < 12; ++j) acc[j] = fzero4();

    auto stageA = [&](int buf, int ks) {
        char* Abuf = lds + buf * 16 * 1024;
        const float* eb = embB + ks * 64;
        #pragma unroll
        for (int j = 0; j < 4; ++j) {
            int chunk = j * 4 + w;
            int r = chunk * 4 + (lane >> 4);
            int c = (lane & 15) ^ (r & 7);
            gl_lds16(eb + (long)r * ED + c * 4, Abuf + chunk * 1024);
        }
    };
    auto stageB = [&](int buf, int ks) {
        char* Bbuf = lds + 32 * 1024 + buf * 24 * 1024;
        const unsigned short* wb = W1p + (size_t)ks * 12288;
        #pragma unroll
        for (int j = 0; j < 6; ++j) {
            int chunk = j * 4 + w;
            gl_lds16(wb + chunk * 512 + lane * 8, Bbuf + chunk * 1024);
        }
    };

    stageA(0, 0); stageB(0, 0);
    __syncthreads();

    int cur = 0;
    for (int ks = 0; ks < 16; ++ks) {
        if (ks < 15) { stageA(cur ^ 1, ks + 1); stageB(cur ^ 1, ks + 1); }
        char* Ac = lds + cur * 16 * 1024;
        char* Bc = lds + 32 * 1024 + cur * 24 * 1024;
        const int r = w * 16 + lr;
        #pragma unroll
        for (int kh = 0; kh < 2; ++kh) {
            int cb0 = kh * 8 + lg * 2;
            float4 fa = *(const float4*)(Ac + r * 256 + ((cb0 ^ (r & 7)) * 16));
            float4 fb = *(const float4*)(Ac + r * 256 + (((cb0 + 1) ^ (r & 7)) * 16));
            bf16x8 a;
            a[0] = (short)f2bf(fa.x); a[1] = (short)f2bf(fa.y);
            a[2] = (short)f2bf(fa.z); a[3] = (short)f2bf(fa.w);
            a[4] = (short)f2bf(fb.x); a[5] = (short)f2bf(fb.y);
            a[6] = (short)f2bf(fb.z); a[7] = (short)f2bf(fb.w);
            #pragma unroll
            for (int n = 0; n < 12; ++n) {
                bf16x8 bv = *(const bf16x8*)(Bc + swz(n * 16 + lr, kh * 64 + lg * 16));
                acc[n] = __builtin_amdgcn_mfma_f32_16x16x32_bf16(a, bv, acc[n], 0, 0, 0);
            }
        }
        __syncthreads();
        cur ^= 1;
    }

    char* H  = lds + w * 2048;
    char* VT = lds + 16 * 1024;

    #pragma unroll
    for (int kq = 0; kq < 2; ++kq) {
        const float* b1 = kq ? qb1 : kb1;
        const float* b2 = kq ? qb2 : kb2;
        unsigned short* dst = kq ? Qo : Ko;
        const float oscale = kq ? SCALE2 : 1.0f;
        #pragma unroll
        for (int n = 0; n < 4; ++n) {
            int col = n * 16 + lr;
            float bias = b1[col];
            #pragma unroll
            for (int rr = 0; rr < 4; ++rr) {
                int row = lg * 4 + rr;
                *(unsigned short*)(H + swz(row, col * 2)) =
                    f2bf(fmaxf(acc[kq * 4 + n][rr] + bias, 0.f));
            }
        }
        lds_fence();
        bf16x8 a2k0 = *(const bf16x8*)(H + swz(lr, 0 * 64 + lg * 16));
        bf16x8 a2k1 = *(const bf16x8*)(H + swz(lr, 1 * 64 + lg * 16));
        lds_fence();

        f32x4 acc2[4];
        #pragma unroll
        for (int n = 0; n < 4; ++n) acc2[n] = fzero4();
        #pragma unroll
        for (int n = 0; n < 4; ++n) {
            bf16x8 w2f0 = *(const bf16x8*)(W2p + ((kq * 4 + n) * 2 + 0) * 512 + lane * 8);
            bf16x8 w2f1 = *(const bf16x8*)(W2p + ((kq * 4 + n) * 2 + 1) * 512 + lane * 8);
            acc2[n] = __builtin_amdgcn_mfma_f32_16x16x32_bf16(a2k0, w2f0, acc2[n], 0, 0, 0);
            acc2[n] = __builtin_amdgcn_mfma_f32_16x16x32_bf16(a2k1, w2f1, acc2[n], 0, 0, 0);
        }
        #pragma unroll
        for (int n = 0; n < 4; ++n) {
            int col = n * 16 + lr;
            float bias = b2[col];
            #pragma unroll
            for (int rr = 0; rr < 4; ++rr) {
                long rg = r0 + w * 16 + lg * 4 + rr;
                dst[rg * KD + col] = f2bf(fmaxf(acc2[n][rr] + bias, 0.f) * oscale);
            }
        }
    }

    #pragma unroll
    for (int n = 0; n < 4; ++n) {
        int col = n * 16 + lr;
        float bias = vb[col];
        #pragma unroll
        for (int rr = 0; rr < 4; ++rr) {
            int tl = w * 16 + lg * 4 + rr;
            *(unsigned short*)(VT + swz(col, tl * 2)) = f2bf(acc[8 + n][rr] + bias);
        }
    }
    __syncthreads();
    #pragma unroll
    for (int it = 0; it < 2; ++it) {
        int c = it * 256 + tid;
        int h = c >> 3, c4 = c & 7;
        *(int4*)(Vt + ((long)b * KD + h) * TCTX + tb + c4 * 8) =
            *(const int4*)(VT + swz(h, c4 * 16));
    }
}

// ---------------------------------------------------------------------------
// Flash attention v7: split-s + K double-buffer + V DIRECT FROM GLOBAL.
// Occupancy is the dominant variable (R7 vs v6 evidence): keep 20KB LDS
// (8 blocks/CU = 16 waves/CU) AND get the 1-barrier/full-tile-cover schedule:
//   tile top: issue K(i+1) DMA -> Kbuf^1 ; load V(i) 16B/lane direct from L2
//   QK^T from Kbuf[cur] (ds_read) ; softmax ; P-bounce (lgkm fences) ; PV(vf)
//   __syncthreads  (drains K-DMA after ~full tile of cover; K reads done)
// V loads are compiler-tracked register loads (no barrier coupling), issued
// ~250cy before PV consumes them. __launch_bounds__(128,4) pins VGPR<=128.
// ---------------------------------------------------------------------------
__global__ __launch_bounds__(128, 4) void attn_kernel(
    const unsigned short* __restrict__ Qb,
    const unsigned short* __restrict__ Kb,
    const unsigned short* __restrict__ Vt,
    float* __restrict__ Opart, float2* __restrict__ MSum)
{
    __shared__ __align__(16) char lds[20 * 1024];
    // K buffers at 0 / 8KB ; per-wave Q/P at 16KB + w*2KB

    const int bid  = blockIdx.x;
    const int half = bid & 1;
    const int rest = bid >> 1;
    const int b    = rest & 7;
    const int qr   = rest >> 3;            // 0..127
    const int qi   = (qr + 127) & 127;     // heavy tiles launch first
    const int t0   = qi * 32;
    const int tid = threadIdx.x, lane = tid & 63, w = tid >> 6;
    const int lr  = lane & 15, lg = lane >> 4;
    const int tg  = t0 + w * 16 + lr;      // this lane's q-row

    char* QP = lds + 16 * 1024 + w * 2048;

    const unsigned short* Qg  = Qb + ((long)b * TCTX + t0 + w * 16) * KD;
    const unsigned short* Kg0 = Kb + (long)b * TCTX * KD;
    const unsigned short* Vg0 = Vt + (long)b * KD * TCTX;

    const int srow = lane >> 3;
    const int sblk = lane & 7;

    // split-s range
    const int s0q = (qi == 127) ? 0 : (qi >> 1);
    const int len = 64 - s0q;
    const int mid = s0q + ((len + 1) >> 1);
    const int s_lo = half ? mid : s0q;
    const int s_hi = half ? 64  : mid;

    auto stageK = [&](int buf, int si) {
        char* Kl = lds + buf * 8 * 1024;
        const unsigned short* Kg = Kg0 + si * 64 * KD;
        #pragma unroll
        for (int j = 0; j < 4; ++j) {
            int chunk = w * 4 + j;             // 2 waves split 8 chunks
            int r = chunk * 8 + srow;
            int c = sblk ^ (r & 7);
            gl_lds16(Kg + r * KD + c * 8, Kl + chunk * 1024);
        }
    };

    float m2 = MASK2, sum_p = 0.f;             // per-lane partial sum
    f32x4 O[4];
    #pragma unroll
    for (int n = 0; n < 4; ++n) O[n] = fzero4();

    if (s_lo < s_hi) {                          // block-uniform
        // prologue: Q + first K
        #pragma unroll
        for (int j = 0; j < 2; ++j) {
            int r = j * 8 + srow;
            int c = sblk ^ (r & 7);
            gl_lds16(Qg + r * KD + c * 8, QP + j * 1024);
        }
        stageK(0, s_lo);
        __syncthreads();                        // Q + K(s_lo) resident

        bf16x8 qf[2];
        #pragma unroll
        for (int kh = 0; kh < 2; ++kh)
            qf[kh] = *(const bf16x8*)(QP + swz(lr, kh * 64 + lg * 16));

        int cur = 0;
        for (int si = s_lo; si < s_hi; ++si) {
            // issue next K tile DMA (drained by end-of-tile barrier)
            if (si + 1 < s_hi) stageK(cur ^ 1, si + 1);

            // V fragments direct from global (L2-hot; compiler-tracked vmcnt)
            const unsigned short* Vg = Vg0 + si * 64;
            bf16x8 vf[2][4];
            #pragma unroll
            for (int kh = 0; kh < 2; ++kh)
                #pragma unroll
                for (int n = 0; n < 4; ++n)
                    vf[kh][n] = *(const bf16x8*)(Vg + (long)(n * 16 + lr) * TCTX + kh * 32 + lg * 8);

            char* Kl = lds + cur * 8 * 1024;

            // ---- QK^T (swapped): C[s][t], t = lr per lane ----
            f32x4 sc[4];
            #pragma unroll
            for (int mi = 0; mi < 4; ++mi) sc[mi] = fzero4();
            __builtin_amdgcn_s_setprio(1);
            #pragma unroll
            for (int kh = 0; kh < 2; ++kh) {
                #pragma unroll
                for (int mi = 0; mi < 4; ++mi) {
                    bf16x8 kf = *(const bf16x8*)(Kl + swz(mi * 16 + lr, kh * 64 + lg * 16));
                    sc[mi] = __builtin_amdgcn_mfma_f32_16x16x32_bf16(kf, qf[kh], sc[mi], 0, 0, 0);
                }
            }
            __builtin_amdgcn_s_setprio(0);

            // ---- mask (scores in exp2 domain via pre-scaled Q) ----
            const int thr = tg - si * 64;       // mask if s_local <= thr
            float s2v[4][4];
            #pragma unroll
            for (int mi = 0; mi < 4; ++mi)
                #pragma unroll
                for (int rr = 0; rr < 4; ++rr) {
                    int sl = mi * 16 + lg * 4 + rr;
                    s2v[mi][rr] = (sl <= thr) ? MASK2 : sc[mi][rr];
                }

            // ---- defer-max online softmax ----
            float pml = s2v[0][0];
            #pragma unroll
            for (int mi = 0; mi < 4; ++mi)
                #pragma unroll
                for (int rr = 0; rr < 4; ++rr) pml = fmaxf(pml, s2v[mi][rr]);

            if (!__all(pml - m2 <= 8.0f)) {     // rare: full rescale
                float pm = pml;
                pm = fmaxf(pm, __shfl_xor(pm, 16, 64));
                pm = fmaxf(pm, __shfl_xor(pm, 32, 64));
                float mnew = fmaxf(m2, pm);
                float scl = __builtin_amdgcn_exp2f(m2 - mnew);
                m2 = mnew;
                sum_p *= scl;
                #pragma unroll
                for (int rr = 0; rr < 4; ++rr) {
                    float sb = __shfl(scl, lg * 4 + rr, 64);
                    #pragma unroll
                    for (int n = 0; n < 4; ++n) O[n][rr] *= sb;
                }
            }
            float ls = 0.f;
            #pragma unroll
            for (int mi = 0; mi < 4; ++mi)
                #pragma unroll
                for (int rr = 0; rr < 4; ++rr) {
                    s2v[mi][rr] = __builtin_amdgcn_exp2f(s2v[mi][rr] - m2);
                    ls += s2v[mi][rr];
                }
            sum_p += ls;

            // ---- pack P -> wave-private LDS (lgkm fence discipline) ----
            #pragma unroll
            for (int mi = 0; mi < 4; ++mi) {
                unsigned lo = cvtpk_bf16(s2v[mi][0], s2v[mi][1]);
                unsigned hi = cvtpk_bf16(s2v[mi][2], s2v[mi][3]);
                *(uint2*)(QP + swz(lr, mi * 32 + lg * 8)) = make_uint2(lo, hi);
            }
            lds_fence();                        // P writes complete
            bf16x8 ap0 = *(const bf16x8*)(QP + swz(lr, 0 * 64 + lg * 16));
            bf16x8 ap1 = *(const bf16x8*)(QP + swz(lr, 1 * 64 + lg * 16));
            lds_fence();                        // P reads returned

            // ---- PV: O += P @ V (register V fragments) ----
            __builtin_amdgcn_s_setprio(1);
            #pragma unroll
            for (int n = 0; n < 4; ++n) {
                O[n] = __builtin_amdgcn_mfma_f32_16x16x32_bf16(ap0, vf[0][n], O[n], 0, 0, 0);
                O[n] = __builtin_amdgcn_mfma_f32_16x16x32_bf16(ap1, vf[1][n], O[n], 0, 0, 0);
            }
            __builtin_amdgcn_s_setprio(0);

            __syncthreads();                    // K reads done; K(si+1) drained
            cur ^= 1;
        }
    }

    // ---- epilogue: write unnormalized partials ----
    float sr = sum_p;
    sr += __shfl_xor(sr, 16, 64);
    sr += __shfl_xor(sr, 32, 64);               // full row sum
    const long rbase = (long)b * TCTX + t0 + w * 16;
    #pragma unroll
    for (int rr = 0; rr < 4; ++rr) {
        int tl = lg * 4 + rr;
        long rowi = (rbase + tl) * 2 + half;
        #pragma unroll
        for (int n = 0; n < 4; ++n)
            Opart[rowi * 64 + n * 16 + lr] = O[n][rr];
    }
    if (lg == 0)
        MSum[(rbase + lr) * 2 + half] = make_float2(m2, sr);
}

// ---------------------------------------------------------------------------
// Combine: merge the two s-halves per row in log2 domain, normalize, write.
// ---------------------------------------------------------------------------
__global__ __launch_bounds__(256) void combine_kernel(
    const float* __restrict__ Opart, const float2* __restrict__ MSum,
    float* __restrict__ out)
{
    const long total = (long)NB * TCTX * KD;
    for (long idx = (long)blockIdx.x * 256 + threadIdx.x; idx < total;
         idx += (long)gridDim.x * 256) {
        long r = idx >> 6;
        int  h = (int)(idx & 63);
        float2 A = MSum[r * 2 + 0];
        float2 B = MSum[r * 2 + 1];
        float M  = fmaxf(A.x, B.x);
        float wa = __builtin_amdgcn_exp2f(A.x - M);
        float wb = __builtin_amdgcn_exp2f(B.x - M);
        float denom = A.y * wa + B.y * wb;
        float oa = Opart[(r * 2 + 0) * 64 + h];
        float ob = Opart[(r * 2 + 1) * 64 + h];
        out[idx] = (oa * wa + ob * wb) / denom;
    }
}

extern "C" void kernel_launch(void* const* d_in, const int* in_sizes, int n_in,
                              void* d_out, int out_size, void* d_ws, size_t ws_size,
                              hipStream_t stream) {
    const float* emb = (const float*)d_in[0];
    const float* kw1 = (const float*)d_in[1];
    const float* kb1 = (const float*)d_in[2];
    const float* kw2 = (const float*)d_in[3];
    const float* kb2 = (const float*)d_in[4];
    const float* qw1 = (const float*)d_in[5];
    const float* qb1 = (const float*)d_in[6];
    const float* qw2 = (const float*)d_in[7];
    const float* qb2 = (const float*)d_in[8];
    const float* vw  = (const float*)d_in[9];
    const float* vb  = (const float*)d_in[10];

    unsigned short* Qb  = (unsigned short*)d_ws;               // 4 MB
    unsigned short* Kb  = Qb + (size_t)NB * TCTX * KD;         // 4 MB
    unsigned short* Vt  = Kb + (size_t)NB * TCTX * KD;         // 4 MB, [b][h][t]
    unsigned short* W1p = Vt + (size_t)NB * TCTX * KD;         // 384 KB
    unsigned short* W2p = W1p + 196608;                        // 16 KB
    float*  Opart = (float*)(W2p + 8192);                      // 16 MB (32768 x 2 x 64)
    float2* MSum  = (float2*)(Opart + (size_t)NB * TCTX * 2 * KD);  // 512 KB

    hipLaunchKernelGGL(prep_kernel, dim3(100), dim3(256), 0, stream,
                       kw1, qw1, vw, kw2, qw2, W1p, W2p);
    hipLaunchKernelGGL(proj_kernel, dim3(512), dim3(256), 0, stream,
                       emb, W1p, W2p, kb1, kb2, qb1, qb2, vb,
                       Qb, Kb, Vt);
    hipLaunchKernelGGL(attn_kernel, dim3(2048), dim3(128), 0, stream,
                       Qb, Kb, Vt, Opart, MSum);
    hipLaunchKernelGGL(combine_kernel, dim3(2048), dim3(256), 0, stream,
                       Opart, MSum, (float*)d_out);
}

// Round 14
// 91.457 us; speedup vs baseline: 1.3616x; 1.3616x over previous
//
#include <hip/hip_runtime.h>
#include <hip/hip_bf16.h>
#include <math.h>

// Problem constants
#define NB   8
#define TCTX 4096
#define ED   1024
#define KD   64

typedef __attribute__((ext_vector_type(8))) short bf16x8;
typedef __attribute__((ext_vector_type(4))) float f32x4;

#define LOG2E  1.44269504088896340736f
#define SCALE2 (0.125f * LOG2E)          // folded into Q at projection time
#define MASK2  (-1e10f * LOG2E)          // -1e10 in log2 domain

// LGKM ops complete OUT OF ORDER: ds_read after ds_write needs lgkmcnt(0)
// (R8/R9 lesson). sched_barrier(0) stops MFMA hoisting past the asm wait.
// (Used in proj only; attn v8 has no LDS P round-trip anymore.)
__device__ __forceinline__ void lds_fence() {
    asm volatile("s_waitcnt lgkmcnt(0)" ::: "memory");
    __builtin_amdgcn_sched_barrier(0);
}

__device__ __forceinline__ unsigned short f2bf(float f) {
    union { float f; unsigned u; } c; c.f = f;
    return (unsigned short)((c.u + 0x7FFFu + ((c.u >> 16) & 1u)) >> 16);
}
__device__ __forceinline__ int swz(int row, int byteoff) {
    return row * 128 + (byteoff ^ ((row & 7) << 4));
}
__device__ __forceinline__ f32x4 fzero4() {
    f32x4 z; z[0] = 0.f; z[1] = 0.f; z[2] = 0.f; z[3] = 0.f; return z;
}
__device__ __forceinline__ void gl_lds16(const void* g, void* l) {
    __builtin_amdgcn_global_load_lds(
        (const __attribute__((address_space(1))) unsigned int*)g,
        (__attribute__((address_space(3))) unsigned int*)l, 16, 0, 0);
}
__device__ __forceinline__ unsigned cvtpk_bf16(float lo, float hi) {
    unsigned r;
    asm("v_cvt_pk_bf16_f32 %0, %1, %2" : "=v"(r) : "v"(lo), "v"(hi));
    return r;
}

// ---------------------------------------------------------------------------
// Prep kernel: one-time weight repack (fp32 -> bf16).  (unchanged, passing)
// ---------------------------------------------------------------------------
__global__ __launch_bounds__(256) void prep_kernel(
    const float* __restrict__ kw1, const float* __restrict__ qw1,
    const float* __restrict__ vw,  const float* __restrict__ kw2,
    const float* __restrict__ qw2,
    unsigned short* __restrict__ W1p, unsigned short* __restrict__ W2p)
{
    int idx = blockIdx.x * 256 + threadIdx.x;   // 16B-block index
    if (idx < 24576) {
        int ks = idx / 1536, rem = idx % 1536;
        int r = rem >> 3, bb = rem & 7;
        int c = bb ^ (r & 7);
        const float* src = (r < 64)  ? (kw1 + r * ED)
                         : (r < 128) ? (qw1 + (r - 64) * ED)
                                     : (vw  + (r - 128) * ED);
        src += ks * 64 + c * 8;
        unsigned short* dst = W1p + (size_t)idx * 8;
        #pragma unroll
        for (int e = 0; e < 8; ++e) dst[e] = f2bf(src[e]);
    } else if (idx < 25600) {
        int j = idx - 24576;
        int lane = j & 63, kh = (j >> 6) & 1, n = (j >> 7) & 3, kq = j >> 9;
        int row = n * 16 + (lane & 15);
        int ko  = kh * 32 + (lane >> 4) * 8;
        const float* src = (kq ? qw2 : kw2) + row * 64 + ko;
        unsigned short* dst = W2p + (size_t)j * 8;
        #pragma unroll
        for (int e = 0; e < 8; ++e) dst[e] = f2bf(src[e]);
    }
}

// ---------------------------------------------------------------------------
// Projection kernel (unchanged, passing).
// ---------------------------------------------------------------------------
__global__ __launch_bounds__(256, 2) void proj_kernel(
    const float* __restrict__ emb,
    const unsigned short* __restrict__ W1p, const unsigned short* __restrict__ W2p,
    const float* __restrict__ kb1, const float* __restrict__ kb2,
    const float* __restrict__ qb1, const float* __restrict__ qb2,
    const float* __restrict__ vb,
    unsigned short* __restrict__ Qo, unsigned short* __restrict__ Ko,
    unsigned short* __restrict__ Vt)
{
    __shared__ __align__(16) char lds[80 * 1024];

    const int tid  = threadIdx.x;
    const int lane = tid & 63;
    const int w    = tid >> 6;
    const int lr   = lane & 15;
    const int lg   = lane >> 4;
    const long r0  = (long)blockIdx.x * 64;
    const int  b   = blockIdx.x >> 6;
    const int  tb  = (blockIdx.x & 63) * 64;

    const float* embB = emb + r0 * ED;

    f32x4 acc[12];
    #pragma unroll
    for (int j = 0; j < 12; ++j) acc[j] = fzero4();

    auto stageA = [&](int buf, int ks) {
        char* Abuf = lds + buf * 16 * 1024;
        const float* eb = embB + ks * 64;
        #pragma unroll
        for (int j = 0; j < 4; ++j) {
            int chunk = j * 4 + w;
            int r = chunk * 4 + (lane >> 4);
            int c = (lane & 15) ^ (r & 7);
            gl_lds16(eb + (long)r * ED + c * 4, Abuf + chunk * 1024);
        }
    };
    auto stageB = [&](int buf, int ks) {
        char* Bbuf = lds + 32 * 1024 + buf * 24 * 1024;
        const unsigned short* wb = W1p + (size_t)ks * 12288;
        #pragma unroll
        for (int j = 0; j < 6; ++j) {
            int chunk = j * 4 + w;
            gl_lds16(wb + chunk * 512 + lane * 8, Bbuf + chunk * 1024);
        }
    };

    stageA(0, 0); stageB(0, 0);
    __syncthreads();

    int cur = 0;
    for (int ks = 0; ks < 16; ++ks) {
        if (ks < 15) { stageA(cur ^ 1, ks + 1); stageB(cur ^ 1, ks + 1); }
        char* Ac = lds + cur * 16 * 1024;
        char* Bc = lds + 32 * 1024 + cur * 24 * 1024;
        const int r = w * 16 + lr;
        #pragma unroll
        for (int kh = 0; kh < 2; ++kh) {
            int cb0 = kh * 8 + lg * 2;
            float4 fa = *(const float4*)(Ac + r * 256 + ((cb0 ^ (r & 7)) * 16));
            float4 fb = *(const float4*)(Ac + r * 256 + (((cb0 + 1) ^ (r & 7)) * 16));
            bf16x8 a;
            a[0] = (short)f2bf(fa.x); a[1] = (short)f2bf(fa.y);
            a[2] = (short)f2bf(fa.z); a[3] = (short)f2bf(fa.w);
            a[4] = (short)f2bf(fb.x); a[5] = (short)f2bf(fb.y);
            a[6] = (short)f2bf(fb.z); a[7] = (short)f2bf(fb.w);
            #pragma unroll
            for (int n = 0; n < 12; ++n) {
                bf16x8 bv = *(const bf16x8*)(Bc + swz(n * 16 + lr, kh * 64 + lg * 16));
                acc[n] = __builtin_amdgcn_mfma_f32_16x16x32_bf16(a, bv, acc[n], 0, 0, 0);
            }
        }
        __syncthreads();
        cur ^= 1;
    }

    char* H  = lds + w * 2048;
    char* VT = lds + 16 * 1024;

    #pragma unroll
    for (int kq = 0; kq < 2; ++kq) {
        const float* b1 = kq ? qb1 : kb1;
        const float* b2 = kq ? qb2 : kb2;
        unsigned short* dst = kq ? Qo : Ko;
        const float oscale = kq ? SCALE2 : 1.0f;
        #pragma unroll
        for (int n = 0; n < 4; ++n) {
            int col = n * 16 + lr;
            float bias = b1[col];
            #pragma unroll
            for (int rr = 0; rr < 4; ++rr) {
                int row = lg * 4 + rr;
                *(unsigned short*)(H + swz(row, col * 2)) =
                    f2bf(fmaxf(acc[kq * 4 + n][rr] + bias, 0.f));
            }
        }
        lds_fence();
        bf16x8 a2k0 = *(const bf16x8*)(H + swz(lr, 0 * 64 + lg * 16));
        bf16x8 a2k1 = *(const bf16x8*)(H + swz(lr, 1 * 64 + lg * 16));
        lds_fence();

        f32x4 acc2[4];
        #pragma unroll
        for (int n = 0; n < 4; ++n) acc2[n] = fzero4();
        #pragma unroll
        for (int n = 0; n < 4; ++n) {
            bf16x8 w2f0 = *(const bf16x8*)(W2p + ((kq * 4 + n) * 2 + 0) * 512 + lane * 8);
            bf16x8 w2f1 = *(const bf16x8*)(W2p + ((kq * 4 + n) * 2 + 1) * 512 + lane * 8);
            acc2[n] = __builtin_amdgcn_mfma_f32_16x16x32_bf16(a2k0, w2f0, acc2[n], 0, 0, 0);
            acc2[n] = __builtin_amdgcn_mfma_f32_16x16x32_bf16(a2k1, w2f1, acc2[n], 0, 0, 0);
        }
        #pragma unroll
        for (int n = 0; n < 4; ++n) {
            int col = n * 16 + lr;
            float bias = b2[col];
            #pragma unroll
            for (int rr = 0; rr < 4; ++rr) {
                long rg = r0 + w * 16 + lg * 4 + rr;
                dst[rg * KD + col] = f2bf(fmaxf(acc2[n][rr] + bias, 0.f) * oscale);
            }
        }
    }

    #pragma unroll
    for (int n = 0; n < 4; ++n) {
        int col = n * 16 + lr;
        float bias = vb[col];
        #pragma unroll
        for (int rr = 0; rr < 4; ++rr) {
            int tl = w * 16 + lg * 4 + rr;
            *(unsigned short*)(VT + swz(col, tl * 2)) = f2bf(acc[8 + n][rr] + bias);
        }
    }
    __syncthreads();
    #pragma unroll
    for (int it = 0; it < 2; ++it) {
        int c = it * 256 + tid;
        int h = c >> 3, c4 = c & 7;
        *(int4*)(Vt + ((long)b * KD + h) * TCTX + tb + c4 * 8) =
            *(const int4*)(VT + swz(h, c4 * 16));
    }
}

// ---------------------------------------------------------------------------
// Flash attention v8: split-s, DMA-only staging, V DOUBLE-BUFFERED in LDS,
// P via cross-lane shfl exchange (no LDS bounce, no lgkm fences).
//   tile: QK^T(K lds)  -> barrier A (no DMA outstanding: free vmcnt)
//         issue K(i+1) + V(i+1)->V[cur^1] DMA
//         softmax ; pack W ; shfl-exchange -> ap ; PV from V[cur]
//         barrier B (drains DMA with ~360cy cover; V reads done)
// LDS 24KB (K 8 + V 2x8) -> 6 blocks/CU = 12 waves/CU. Q staged via V1 at
// prologue (read to regs before V1's first overwrite, ordered by barrier A).
// XCD-aware bid: b = bid&7 pins each batch's K/Vt (2MB) to one XCD L2.
// Exchange map (verified): ap[kh] word jj = W[2kh+(lg>>1)][jj&1] taken from
// lane ((2*(lg&1)+(jj>>1))<<4)|lr, where W[mi][j]=cvtpk(s2v[mi][2j],[2j+1]).
// ---------------------------------------------------------------------------
__global__ __launch_bounds__(128) void attn_kernel(
    const unsigned short* __restrict__ Qb,
    const unsigned short* __restrict__ Kb,
    const unsigned short* __restrict__ Vt,
    float* __restrict__ Opart, float2* __restrict__ MSum)
{
    __shared__ __align__(16) char lds[24 * 1024];
    // K at 0 (8KB), V0 at 8KB, V1 at 16KB

    const int bid  = blockIdx.x;
    const int b    = bid & 7;              // XCD-pinned batch
    const int half = (bid >> 3) & 1;
    const int qr   = bid >> 4;             // 0..127
    const int qi   = (qr + 127) & 127;     // heavy tiles launch first
    const int t0   = qi * 32;
    const int tid = threadIdx.x, lane = tid & 63, w = tid >> 6;
    const int lr  = lane & 15, lg = lane >> 4;
    const int tg  = t0 + w * 16 + lr;      // this lane's q-row

    const unsigned short* Qg  = Qb + ((long)b * TCTX + t0 + w * 16) * KD;
    const unsigned short* Kg0 = Kb + (long)b * TCTX * KD;
    const unsigned short* Vg0 = Vt + (long)b * KD * TCTX;

    const int srow = lane >> 3;
    const int sblk = lane & 7;

    // split-s range
    const int s0q = (qi == 127) ? 0 : (qi >> 1);
    const int len = 64 - s0q;
    const int mid = s0q + ((len + 1) >> 1);
    const int s_lo = half ? mid : s0q;
    const int s_hi = half ? 64  : mid;

    auto stageK = [&](int si) {
        const unsigned short* Kg = Kg0 + si * 64 * KD;
        #pragma unroll
        for (int j = 0; j < 4; ++j) {
            int chunk = w * 4 + j;             // 2 waves split 8 chunks
            int r = chunk * 8 + srow;
            int c = sblk ^ (r & 7);
            gl_lds16(Kg + r * KD + c * 8, lds + chunk * 1024);
        }
    };
    auto stageV = [&](int buf, int si) {
        char* Vl = lds + 8 * 1024 + buf * 8 * 1024;
        const unsigned short* Vg = Vg0 + si * 64;
        #pragma unroll
        for (int j = 0; j < 4; ++j) {
            int chunk = w * 4 + j;
            int r = chunk * 8 + srow;
            int c = sblk ^ (r & 7);
            gl_lds16(Vg + (long)r * TCTX + c * 8, Vl + chunk * 1024);
        }
    };

    float m2 = MASK2, sum_p = 0.f;             // per-lane partial sum
    f32x4 O[4];
    #pragma unroll
    for (int n = 0; n < 4; ++n) O[n] = fzero4();

    if (s_lo < s_hi) {                          // block-uniform
        // prologue: Q -> V1 region (per-wave 2KB), K(s_lo), V(s_lo) -> V0
        char* QP = lds + 16 * 1024 + w * 2048;
        #pragma unroll
        for (int j = 0; j < 2; ++j) {
            int r = j * 8 + srow;
            int c = sblk ^ (r & 7);
            gl_lds16(Qg + r * KD + c * 8, QP + j * 1024);
        }
        stageK(s_lo);
        stageV(0, s_lo);
        __syncthreads();                        // all prologue DMA resident

        bf16x8 qf[2];
        #pragma unroll
        for (int kh = 0; kh < 2; ++kh)
            qf[kh] = *(const bf16x8*)(QP + swz(lr, kh * 64 + lg * 16));
        // qf reads drain at barrier A of the first tile, before V1 overwrite

        int cur = 0;
        for (int si = s_lo; si < s_hi; ++si) {
            // ---- QK^T (swapped): C[s][t], t = lr per lane ----
            f32x4 sc[4];
            #pragma unroll
            for (int mi = 0; mi < 4; ++mi) sc[mi] = fzero4();
            __builtin_amdgcn_s_setprio(1);
            #pragma unroll
            for (int kh = 0; kh < 2; ++kh) {
                #pragma unroll
                for (int mi = 0; mi < 4; ++mi) {
                    bf16x8 kf = *(const bf16x8*)(lds + swz(mi * 16 + lr, kh * 64 + lg * 16));
                    sc[mi] = __builtin_amdgcn_mfma_f32_16x16x32_bf16(kf, qf[kh], sc[mi], 0, 0, 0);
                }
            }
            __builtin_amdgcn_s_setprio(0);

            __syncthreads();                    // A: K reads done (vmcnt free)
            if (si + 1 < s_hi) {                // DMA flies under rest of tile
                stageK(si + 1);
                stageV(cur ^ 1, si + 1);
            }

            // ---- mask (scores in exp2 domain via pre-scaled Q) ----
            const int thr = tg - si * 64;       // mask if s_local <= thr
            float s2v[4][4];
            #pragma unroll
            for (int mi = 0; mi < 4; ++mi)
                #pragma unroll
                for (int rr = 0; rr < 4; ++rr) {
                    int sl = mi * 16 + lg * 4 + rr;
                    s2v[mi][rr] = (sl <= thr) ? MASK2 : sc[mi][rr];
                }

            // ---- defer-max online softmax ----
            float pml = s2v[0][0];
            #pragma unroll
            for (int mi = 0; mi < 4; ++mi)
                #pragma unroll
                for (int rr = 0; rr < 4; ++rr) pml = fmaxf(pml, s2v[mi][rr]);

            if (!__all(pml - m2 <= 8.0f)) {     // rare: full rescale
                float pm = pml;
                pm = fmaxf(pm, __shfl_xor(pm, 16, 64));
                pm = fmaxf(pm, __shfl_xor(pm, 32, 64));
                float mnew = fmaxf(m2, pm);
                float scl = __builtin_amdgcn_exp2f(m2 - mnew);
                m2 = mnew;
                sum_p *= scl;
                #pragma unroll
                for (int rr = 0; rr < 4; ++rr) {
                    float sb = __shfl(scl, lg * 4 + rr, 64);
                    #pragma unroll
                    for (int n = 0; n < 4; ++n) O[n][rr] *= sb;
                }
            }
            float ls = 0.f;
            #pragma unroll
            for (int mi = 0; mi < 4; ++mi)
                #pragma unroll
                for (int rr = 0; rr < 4; ++rr) {
                    s2v[mi][rr] = __builtin_amdgcn_exp2f(s2v[mi][rr] - m2);
                    ls += s2v[mi][rr];
                }
            sum_p += ls;

            // ---- pack P words; cross-lane shfl exchange -> A-fragments ----
            unsigned W[4][2];
            #pragma unroll
            for (int mi = 0; mi < 4; ++mi) {
                W[mi][0] = cvtpk_bf16(s2v[mi][0], s2v[mi][1]);
                W[mi][1] = cvtpk_bf16(s2v[mi][2], s2v[mi][3]);
            }
            const int lgh  = lg >> 1;
            const int bsrc = 2 * (lg & 1);
            union { unsigned u[4]; bf16x8 v; } apu0, apu1;
            #pragma unroll
            for (int jj = 0; jj < 4; ++jj) {
                int srcl = ((bsrc + (jj >> 1)) << 4) | lr;
                unsigned lo0 = __shfl(W[0][jj & 1], srcl, 64);
                unsigned hi0 = __shfl(W[1][jj & 1], srcl, 64);
                unsigned lo1 = __shfl(W[2][jj & 1], srcl, 64);
                unsigned hi1 = __shfl(W[3][jj & 1], srcl, 64);
                apu0.u[jj] = lgh ? hi0 : lo0;
                apu1.u[jj] = lgh ? hi1 : lo1;
            }

            // ---- PV: O += P @ V from V[cur] ----
            char* Vl = lds + 8 * 1024 + cur * 8 * 1024;
            __builtin_amdgcn_s_setprio(1);
            #pragma unroll
            for (int n = 0; n < 4; ++n) {
                bf16x8 bv0 = *(const bf16x8*)(Vl + swz(n * 16 + lr, 0 * 64 + lg * 16));
                bf16x8 bv1 = *(const bf16x8*)(Vl + swz(n * 16 + lr, 1 * 64 + lg * 16));
                O[n] = __builtin_amdgcn_mfma_f32_16x16x32_bf16(apu0.v, bv0, O[n], 0, 0, 0);
                O[n] = __builtin_amdgcn_mfma_f32_16x16x32_bf16(apu1.v, bv1, O[n], 0, 0, 0);
            }
            __builtin_amdgcn_s_setprio(0);

            __syncthreads();                    // B: DMA drained (~360cy cover)
            cur ^= 1;
        }
    }

    // ---- epilogue: write unnormalized partials ----
    float sr = sum_p;
    sr += __shfl_xor(sr, 16, 64);
    sr += __shfl_xor(sr, 32, 64);               // full row sum
    const long rbase = (long)b * TCTX + t0 + w * 16;
    #pragma unroll
    for (int rr = 0; rr < 4; ++rr) {
        int tl = lg * 4 + rr;
        long rowi = (rbase + tl) * 2 + half;
        #pragma unroll
        for (int n = 0; n < 4; ++n)
            Opart[rowi * 64 + n * 16 + lr] = O[n][rr];
    }
    if (lg == 0)
        MSum[(rbase + lr) * 2 + half] = make_float2(m2, sr);
}

// ---------------------------------------------------------------------------
// Combine: merge the two s-halves per row in log2 domain, normalize, write.
// ---------------------------------------------------------------------------
__global__ __launch_bounds__(256) void combine_kernel(
    const float* __restrict__ Opart, const float2* __restrict__ MSum,
    float* __restrict__ out)
{
    const long total = (long)NB * TCTX * KD;
    for (long idx = (long)blockIdx.x * 256 + threadIdx.x; idx < total;
         idx += (long)gridDim.x * 256) {
        long r = idx >> 6;
        int  h = (int)(idx & 63);
        float2 A = MSum[r * 2 + 0];
        float2 B = MSum[r * 2 + 1];
        float M  = fmaxf(A.x, B.x);
        float wa = __builtin_amdgcn_exp2f(A.x - M);
        float wb = __builtin_amdgcn_exp2f(B.x - M);
        float denom = A.y * wa + B.y * wb;
        float oa = Opart[(r * 2 + 0) * 64 + h];
        float ob = Opart[(r * 2 + 1) * 64 + h];
        out[idx] = (oa * wa + ob * wb) / denom;
    }
}

extern "C" void kernel_launch(void* const* d_in, const int* in_sizes, int n_in,
                              void* d_out, int out_size, void* d_ws, size_t ws_size,
                              hipStream_t stream) {
    const float* emb = (const float*)d_in[0];
    const float* kw1 = (const float*)d_in[1];
    const float* kb1 = (const float*)d_in[2];
    const float* kw2 = (const float*)d_in[3];
    const float* kb2 = (const float*)d_in[4];
    const float* qw1 = (const float*)d_in[5];
    const float* qb1 = (const float*)d_in[6];
    const float* qw2 = (const float*)d_in[7];
    const float* qb2 = (const float*)d_in[8];
    const float* vw  = (const float*)d_in[9];
    const float* vb  = (const float*)d_in[10];

    unsigned short* Qb  = (unsigned short*)d_ws;               // 4 MB
    unsigned short* Kb  = Qb + (size_t)NB * TCTX * KD;         // 4 MB
    unsigned short* Vt  = Kb + (size_t)NB * TCTX * KD;         // 4 MB, [b][h][t]
    unsigned short* W1p = Vt + (size_t)NB * TCTX * KD;         // 384 KB
    unsigned short* W2p = W1p + 196608;                        // 16 KB
    float*  Opart = (float*)(W2p + 8192);                      // 16 MB (32768 x 2 x 64)
    float2* MSum  = (float2*)(Opart + (size_t)NB * TCTX * 2 * KD);  // 512 KB

    hipLaunchKernelGGL(prep_kernel, dim3(100), dim3(256), 0, stream,
                       kw1, qw1, vw, kw2, qw2, W1p, W2p);
    hipLaunchKernelGGL(proj_kernel, dim3(512), dim3(256), 0, stream,
                       emb, W1p, W2p, kb1, kb2, qb1, qb2, vb,
                       Qb, Kb, Vt);
    hipLaunchKernelGGL(attn_kernel, dim3(2048), dim3(128), 0, stream,
                       Qb, Kb, Vt, Opart, MSum);
    hipLaunchKernelGGL(combine_kernel, dim3(2048), dim3(256), 0, stream,
                       Opart, MSum, (float*)d_out);
}